// Round 6
// baseline (172.959 us; speedup 1.0000x reference)
//
#include <hip/hip_runtime.h>
#include <hip/hip_bf16.h>

// Problem constants (B,H,L,D = 2,16,2048,64)
#define BB 2
#define HH 16
#define LL 2048
#define DD 64
constexpr int BH = BB * HH;   // 32 heads
constexpr int NT = LL / 64;   // 32 tiles of 64

typedef __attribute__((ext_vector_type(8))) short bf16x8;  // 8 bf16 (4 VGPR)
typedef __attribute__((ext_vector_type(4))) float f32x4;   // 4 f32

typedef unsigned short u16;
typedef unsigned int u32;

__device__ __forceinline__ u16 f2bf(float x) {
    __bf16 b = (__bf16)x;          // RNE convert
    u16 u; __builtin_memcpy(&u, &b, 2);
    return u;
}
__device__ __forceinline__ float bf2f(u16 u) {
    union { u32 i; float f; } c; c.i = ((u32)u) << 16; return c.f;
}

// async global->LDS, 16B per lane; lds dest = wave-uniform base + lane*16
__device__ __forceinline__ void gll16(const void* gptr, void* ldsptr) {
    __builtin_amdgcn_global_load_lds(
        (const u32 __attribute__((address_space(1)))*)gptr,
        (u32 __attribute__((address_space(3)))*)ldsptr, 16, 0, 0);
}

// fragment read: one ds_read_b128 from a swizzled row-major [64][64] bf16 tile.
__device__ __forceinline__ bf16x8 ld_frag(const char* tile, int row, int kbyte) {
    return *(const bf16x8*)(tile + row * 128 + (kbyte ^ ((row & 7) << 4)));
}

// ---------------------------------------------------------------------------
// fmap2: hi = bf16(relu(x @ W)) per head, pre-swizzled 64x64 tiles.
// TSUM: per-tile per-dim column sums of the ROUNDED bf16 values (consistency
// with what the MFMAs consume).
// ---------------------------------------------------------------------------
template<bool TSUM>
__global__ __launch_bounds__(256) void fmap2_kernel(
    const float* __restrict__ x, const float* __restrict__ W,
    u16* __restrict__ ghi, float* __restrict__ tsum)
{
    __shared__ float sXT[64][64];
    __shared__ float sW[64][64];
    int bx = blockIdx.x;
    int bh = bx / NT, rb = bx % NT;
    int h = bh % HH;
    const float* xp = x + (size_t)bh * LL * DD + (size_t)rb * 64 * DD;
    const float* wp = W + (size_t)h * DD * DD;

    int tid = threadIdx.x;
    {
        int r = tid >> 2, c0 = (tid & 3) * 16;
        for (int u = 0; u < 16; u += 4) {
            float4 t = *(const float4*)(xp + r * DD + c0 + u);
            sXT[c0 + u + 0][r] = t.x; sXT[c0 + u + 1][r] = t.y;
            sXT[c0 + u + 2][r] = t.z; sXT[c0 + u + 3][r] = t.w;
            *(float4*)(&sW[r][c0 + u]) = *(const float4*)(wp + r * DD + c0 + u);
        }
    }
    __syncthreads();

    int ty = tid >> 4, tx = tid & 15;
    float acc[4][4] = {};
    #pragma unroll 4
    for (int d = 0; d < 64; ++d) {
        float4 a = *(const float4*)(&sXT[d][ty * 4]);
        float4 b = *(const float4*)(&sW[d][tx * 4]);
        float av[4] = {a.x, a.y, a.z, a.w};
        float bv[4] = {b.x, b.y, b.z, b.w};
        #pragma unroll
        for (int j = 0; j < 4; ++j)
            #pragma unroll
            for (int i = 0; i < 4; ++i)
                acc[j][i] = fmaf(av[j], bv[i], acc[j][i]);
    }

    char* hib = (char*)ghi + (size_t)bx * 8192;
    float colsum[4] = {0.f, 0.f, 0.f, 0.f};
    #pragma unroll
    for (int j = 0; j < 4; ++j) {
        int rr = ty * 4 + j;
        ushort4 hv;
        hv.x = f2bf(fmaxf(acc[j][0], 0.f));
        hv.y = f2bf(fmaxf(acc[j][1], 0.f));
        hv.z = f2bf(fmaxf(acc[j][2], 0.f));
        hv.w = f2bf(fmaxf(acc[j][3], 0.f));
        int off = rr * 128 + ((tx * 8) ^ ((rr & 7) << 4));
        *(ushort4*)(hib + off) = hv;
        if constexpr (TSUM) {
            colsum[0] += bf2f(hv.x); colsum[1] += bf2f(hv.y);
            colsum[2] += bf2f(hv.z); colsum[3] += bf2f(hv.w);
        }
    }

    if constexpr (TSUM) {
        __syncthreads();           // safe to reuse sXT
        #pragma unroll
        for (int i = 0; i < 4; ++i)
            sXT[ty][tx * 4 + i] = colsum[i];
        __syncthreads();
        if (tid < 64) {
            float s = 0.f;
            #pragma unroll
            for (int y = 0; y < 16; ++y) s += sXT[y][tid];
            tsum[(size_t)bx * 64 + tid] = s;
        }
    }
}

// ---------------------------------------------------------------------------
// vprep: V fp32 [c][e] -> VT bf16 swizzled tiles [e][c]
// ---------------------------------------------------------------------------
__global__ __launch_bounds__(256) void vprep_kernel(
    const float* __restrict__ v, u16* __restrict__ vt)
{
    int bx = blockIdx.x;
    int bh = bx >> 5, ct = bx & 31;
    int t = threadIdx.x;
    int c0 = (t >> 4) * 4, e0 = (t & 15) * 4;
    const float* vp = v + ((size_t)bh * LL + (size_t)ct * 64) * DD;

    float ld[4][4];
    #pragma unroll
    for (int j = 0; j < 4; ++j) {
        float4 f = *(const float4*)(vp + (size_t)(c0 + j) * DD + e0);
        ld[j][0] = f.x; ld[j][1] = f.y; ld[j][2] = f.z; ld[j][3] = f.w;
    }
    char* base = (char*)vt + (size_t)bx * 8192;
    #pragma unroll
    for (int i = 0; i < 4; ++i) {
        int e = e0 + i;
        ushort4 wv;
        wv.x = f2bf(ld[0][i]); wv.y = f2bf(ld[1][i]);
        wv.z = f2bf(ld[2][i]); wv.w = f2bf(ld[3][i]);
        *(ushort4*)(base + e * 128 + ((c0 * 2) ^ ((e & 7) << 4))) = wv;
    }
}

// ---------------------------------------------------------------------------
// tprefix: per-head exclusive prefix over the 32 per-tile sums. 32 blk x 64 thr.
// ---------------------------------------------------------------------------
__global__ __launch_bounds__(64) void tprefix_kernel(
    const float* __restrict__ tsum, float* __restrict__ pex)
{
    int bh = blockIdx.x, d = threadIdx.x;
    float run = 0.f;
    for (int t = 0; t < NT; ++t) {
        size_t i = ((size_t)bh * NT + t) * 64 + d;
        pex[i] = run;
        run += tsum[i];
    }
}

// ---------------------------------------------------------------------------
// rowsum: rinv[bh][r] = 1 / (fq_r . cumsum(fk)_r). 1024 blocks, 4 waves each;
// wave w owns 16 rows of the tile; lane = dim.
// ---------------------------------------------------------------------------
__global__ __launch_bounds__(256) void rowsum_kernel(
    const u16* __restrict__ khi, const u16* __restrict__ qhi,
    const float* __restrict__ pex, float* __restrict__ rinv)
{
    __shared__ float wsum[4][64];
    int bx = blockIdx.x;
    int bh = bx >> 5, t = bx & 31;
    int w = threadIdx.x >> 6, d = threadIdx.x & 63;
    const size_t tb = ((size_t)bh * NT + t) * 4096;

    float fkv[16];
    float s = 0.f;
    #pragma unroll
    for (int i = 0; i < 16; ++i) {
        int r = w * 16 + i;
        size_t idx = tb + r * 64 + (d ^ ((r & 7) << 3));
        fkv[i] = bf2f(khi[idx]);
        s += fkv[i];
    }
    wsum[w][d] = s;
    __syncthreads();

    float cs = pex[((size_t)bh * NT + t) * 64 + d];
    for (int w2 = 0; w2 < w; ++w2) cs += wsum[w2][d];

    #pragma unroll
    for (int i = 0; i < 16; ++i) {
        int r = w * 16 + i;
        size_t idx = tb + r * 64 + (d ^ ((r & 7) << 3));
        cs += fkv[i];
        float tt = bf2f(qhi[idx]) * cs;
        #pragma unroll
        for (int o = 1; o < 64; o <<= 1) tt += __shfl_xor(tt, o);
        if (d == 0) rinv[(size_t)bh * LL + t * 64 + r] = 1.0f / tt;
    }
}

// ---------------------------------------------------------------------------
// attn4: single-bf16 MFMA kernel, double-buffered, 40KB LDS -> 4 blocks/CU.
// LDS: buf0[16K: K|VT] buf1[16K] sS[8K].
// Per tile: stage(t+1) -> QK^T -> mask/normalize -> sS(bf16) -> raw barrier
// (lgkm only) -> coop full-line attn store + PV -> __syncthreads.
// ---------------------------------------------------------------------------
__global__ __launch_bounds__(256, 4) void attn4_kernel(
    const u16* __restrict__ qhi, const u16* __restrict__ khi,
    const u16* __restrict__ vt, const float* __restrict__ rinvg,
    float* __restrict__ outO, float* __restrict__ outA)
{
    __shared__ __align__(16) char lds[40960];
    char* sS = lds + 32768;

    int bx = blockIdx.x;
    // XCD-grouping: 4 consecutive heads per XCD; interleave long/short rblk
    int bh = (bx & 7) * 4 + (bx >> 8);
    int jj = (bx >> 3) & 31;
    int rblk = (jj & 1) ? (jj >> 1) : (31 - (jj >> 1));
    int brow = rblk * 64;

    int tid = threadIdx.x;
    int w = tid >> 6, l = tid & 63;
    int l15 = l & 15, lq = l >> 4;
    int o = tid * 16, wb = w << 10;

    // ---- prologue: stage Q -> buf1 area, tile0 K/VT -> buf0 ----
    {
        const char* qT = (const char*)qhi + ((size_t)bh * NT + rblk) * 8192;
        gll16(qT + o,        lds + 16384 + wb);
        gll16(qT + o + 4096, lds + 16384 + wb + 4096);

        const char* kT = (const char*)khi + (size_t)bh * NT * 8192;
        const char* vT = (const char*)vt  + (size_t)bh * NT * 8192;
        gll16(kT + o,        lds + wb);
        gll16(kT + o + 4096, lds + wb + 4096);
        gll16(vT + o,        lds + 8192 + wb);
        gll16(vT + o + 4096, lds + 8192 + wb + 4096);
    }
    float ri = rinvg[(size_t)bh * LL + brow + w * 16 + l15];
    asm volatile("s_waitcnt vmcnt(0)" ::: "memory");
    __syncthreads();

    // Q fragments to registers
    int qrow = w * 16 + l15;
    bf16x8 bq[2];
    #pragma unroll
    for (int ks = 0; ks < 2; ++ks)
        bq[ks] = ld_frag(lds + 16384, qrow, lq * 16 + ks * 64);
    __syncthreads();   // Q region safe to reuse as buf1

    f32x4 acc2[4];
    #pragma unroll
    for (int eb = 0; eb < 4; ++eb) acc2[eb] = (f32x4){0.f, 0.f, 0.f, 0.f};

    for (int ct = 0; ct <= rblk; ++ct) {
        char* cur = lds + (ct & 1) * 16384;

        if (ct < rblk) {   // stage next tile into the other buffer
            char* nxt = lds + ((ct + 1) & 1) * 16384;
            const char* kT = (const char*)khi + ((size_t)bh * NT + ct + 1) * 8192;
            const char* vT = (const char*)vt  + ((size_t)bh * NT + ct + 1) * 8192;
            gll16(kT + o,        nxt + wb);
            gll16(kT + o + 4096, nxt + wb + 4096);
            gll16(vT + o,        nxt + 8192 + wb);
            gll16(vT + o + 4096, nxt + 8192 + wb + 4096);
        }

        // QK^T: S^T quadrants (single bf16 pass)
        f32x4 sa[4];
        #pragma unroll
        for (int cb = 0; cb < 4; ++cb) sa[cb] = (f32x4){0.f, 0.f, 0.f, 0.f};
        #pragma unroll
        for (int ks = 0; ks < 2; ++ks) {
            #pragma unroll
            for (int cb = 0; cb < 4; ++cb) {
                bf16x8 ah = ld_frag(cur, cb * 16 + l15, lq * 16 + ks * 64);
                sa[cb] = __builtin_amdgcn_mfma_f32_16x16x32_bf16(ah, bq[ks], sa[cb], 0, 0, 0);
            }
        }

        bool diag = (ct == rblk);
        int srow = w * 16 + l15;
        #pragma unroll
        for (int cb = 0; cb < 4; ++cb) {
            if (diag) {
                #pragma unroll
                for (int rg = 0; rg < 4; ++rg)
                    if (cb * 16 + lq * 4 + rg > srow) sa[cb][rg] = 0.f;
            }
            sa[cb] *= ri;
            ushort4 pv;
            pv.x = f2bf(sa[cb][0]); pv.y = f2bf(sa[cb][1]);
            pv.z = f2bf(sa[cb][2]); pv.w = f2bf(sa[cb][3]);
            int soff = srow * 128 + ((cb * 32 + lq * 8) ^ ((srow & 7) << 4));
            *(ushort4*)(sS + soff) = pv;
        }

        // make sS visible to all waves WITHOUT draining vmcnt (stage in flight)
        asm volatile("s_waitcnt lgkmcnt(0)" ::: "memory");
        __builtin_amdgcn_sched_barrier(0);
        __builtin_amdgcn_s_barrier();
        __builtin_amdgcn_sched_barrier(0);

        // cooperative full-line attn store: 16 lanes cover one row's 256B
        {
            int bcol = ct * 64;
            float* atile = outA + ((size_t)bh * LL + brow) * LL + bcol;
            #pragma unroll
            for (int u = 0; u < 4; ++u) {
                int idx = tid + u * 256;
                int r = idx >> 4;
                int c = idx & 15;
                ushort4 pv = *(const ushort4*)(sS + r * 128 + ((c * 8) ^ ((r & 7) << 4)));
                f32x4 o4 = { bf2f(pv.x), bf2f(pv.y), bf2f(pv.z), bf2f(pv.w) };
                __builtin_nontemporal_store(o4, (f32x4*)(atile + (size_t)r * LL + c * 4));
            }
        }

        // PV: out^T += V^T @ S^T
        bf16x8 pf[2];
        #pragma unroll
        for (int ks = 0; ks < 2; ++ks)
            pf[ks] = ld_frag(sS, srow, lq * 16 + ks * 64);
        #pragma unroll
        for (int ks = 0; ks < 2; ++ks) {
            #pragma unroll
            for (int eb = 0; eb < 4; ++eb) {
                bf16x8 av = ld_frag(cur + 8192, eb * 16 + l15, lq * 16 + ks * 64);
                acc2[eb] = __builtin_amdgcn_mfma_f32_16x16x32_bf16(av, pf[ks], acc2[eb], 0, 0, 0);
            }
        }

        __syncthreads();   // drain (stage latency already hidden) + buffer handoff
    }

    // zero-fill strictly-above-diagonal attn tiles (full-line coalesced)
    f32x4 z = {0.f, 0.f, 0.f, 0.f};
    for (int ct2 = rblk + 1; ct2 < NT; ++ct2) {
        int bcol = ct2 * 64;
        #pragma unroll
        for (int u = 0; u < 4; ++u) {
            int idx = tid + u * 256;
            int r = idx >> 4, c4 = idx & 15;
            __builtin_nontemporal_store(z,
                (f32x4*)(outA + ((size_t)bh * LL + brow + r) * LL + bcol + c4 * 4));
        }
    }

    // out write (from out^T accumulators)
    float* oo = outO + ((size_t)bh * LL + brow + w * 16 + l15) * DD;
    #pragma unroll
    for (int eb = 0; eb < 4; ++eb) {
        float4 o4 = { acc2[eb][0], acc2[eb][1], acc2[eb][2], acc2[eb][3] };
        *(float4*)(oo + eb * 16 + lq * 4) = o4;
    }
}

// ---------------------------------------------------------------------------
extern "C" void kernel_launch(void* const* d_in, const int* in_sizes, int n_in,
                              void* d_out, int out_size, void* d_ws, size_t ws_size,
                              hipStream_t stream)
{
    (void)in_sizes; (void)n_in; (void)out_size; (void)ws_size;
    const float* q  = (const float*)d_in[0];
    const float* k  = (const float*)d_in[1];
    const float* v  = (const float*)d_in[2];
    const float* Wq = (const float*)d_in[3];
    const float* Wk = (const float*)d_in[4];

    float* out  = (float*)d_out;                       // [B,H,L,D]
    float* attn = out + (size_t)BB * HH * LL * DD;     // [B,H,L,L]

    const size_t TILE_HW = (size_t)BH * NT * 4096;     // halfwords per bf16 array
    u16* QHI = (u16*)d_ws;
    u16* KHI = QHI + TILE_HW;
    u16* VT  = KHI + TILE_HW;
    float* RINV = (float*)(VT + TILE_HW);              // [BH, L]
    float* TSUM = RINV + (size_t)BH * LL;              // [BH, NT, 64]
    float* PEX  = TSUM + (size_t)BH * NT * 64;         // [BH, NT, 64]

    // NOTE reference swap: fq uses fm_k_weight, fk uses fm_q_weight.
    fmap2_kernel<false><<<BH * NT, 256, 0, stream>>>(q, Wk, QHI, nullptr);
    fmap2_kernel<true><<<BH * NT, 256, 0, stream>>>(k, Wq, KHI, TSUM);
    vprep_kernel<<<BH * NT, 256, 0, stream>>>(v, VT);
    tprefix_kernel<<<BH, 64, 0, stream>>>(TSUM, PEX);
    rowsum_kernel<<<BH * NT, 256, 0, stream>>>(KHI, QHI, PEX, RINV);
    attn4_kernel<<<BH * NT, 256, 0, stream>>>(QHI, KHI, VT, RINV, out, attn);
}